// Round 21
// baseline (43.605 us; speedup 1.0000x reference)
//
#include <hip/hip_runtime.h>
#include <hip/hip_bf16.h>

// 5-layer MLP 30->64->32->16->8->2 with ReLU, bf16 MFMA (16x16x32), batch tile N=16.
// Register-resident layer chain (k-slot map k = 4g+(i&3)+16*(i>>2); C/D layout
// m = 16t+4g+q, same lane group -> inter-layer repack is lane-local).
// Round-21 = R15 champion with a VGPR-band cut (84 -> target <=64 = 8 waves/SIMD,
// m69 occupancy bands), achieved WITHOUT launch-bounds forcing (R7 spill lesson):
//  (1) rB prefetch set removed: after writeslot(rA) the rA regs are dead, so
//      the next pair loads IN-PLACE (WAR ordering free; same 1-iteration
//      latency hiding; -16 VGPR, -8 movs/iter).
//  (2) bias1[4] removed: b1 folded into A1's k=30 column with 1.0 fed in B0's
//      g==3 slot (R2-R4 proven scheme; k=31 zero); layer-1 C-init = zero.
//  (3) grid cap 1280 -> 2048 (17.4 KB LDS x 8 blocks = 139 KB <= 160 KB) so
//      the doubled waves/SIMD can actually be resident.

typedef float        f32x4 __attribute__((ext_vector_type(4)));
typedef unsigned int u32x4 __attribute__((ext_vector_type(4)));
typedef short        s16x8 __attribute__((ext_vector_type(8)));

// a -> low 16 bits, b -> high 16 bits; round-half-up (proven R14/R15)
static __device__ __forceinline__ unsigned int pkbf(float a, float b) {
    unsigned int ua = __builtin_bit_cast(unsigned int, a) + 0x8000u;
    unsigned int ub = __builtin_bit_cast(unsigned int, b) + 0x8000u;
    return __builtin_amdgcn_perm(ub, ua, 0x07060302u);
}
static __device__ __forceinline__ unsigned int rp2(float a, float b) {
    return pkbf(fmaxf(a, 0.0f), fmaxf(b, 0.0f));
}
// weights (preamble only): exact RNE via header
static __device__ __forceinline__ unsigned short f2bf(float f) {
    __hip_bfloat16 h = __float2bfloat16(f);
    unsigned short r;
    __builtin_memcpy(&r, &h, sizeof(r));
    return r;
}

#define MFMA(A, B, C) __builtin_amdgcn_mfma_f32_16x16x32_bf16((A), (B), (C), 0, 0, 0)

// Per-wave LDS: ONE slot of 4096 B window + 256 B zeroed pad (R15 layout).
#define SLOT_B 4352

__global__ __launch_bounds__(256) void mlp_mfma_kernel(
    const float* __restrict__ x,
    const float* __restrict__ w1, const float* __restrict__ b1,
    const float* __restrict__ w2, const float* __restrict__ b2,
    const float* __restrict__ w3, const float* __restrict__ b3,
    const float* __restrict__ w4, const float* __restrict__ b4,
    const float* __restrict__ w5, const float* __restrict__ b5,
    float* __restrict__ out, int n)
{
    __shared__ __attribute__((aligned(16))) unsigned char ldsX[4][SLOT_B];

    const int lane = threadIdx.x & 63;
    const int wv   = threadIdx.x >> 6;
    const int g    = lane >> 4;
    const int ml   = lane & 15;

    unsigned char* myL = &ldsX[wv][0];

    // zero the 256 B pad (row-31 g==3 overread must be finite; 0 * 0-wt = 0)
    *(unsigned int*)(myL + 4096 + lane * 4) = 0u;

    // ---- per-wave weight / bias fragment build ----
    // A1: k<30 -> w1 column; k==30 -> b1 (multiplied by the constant 1.0 fed
    // in B0's g==3 slot); k==31 -> 0.
    s16x8 A1[4], A2[2][2], A3, A4, A5;
    #pragma unroll
    for (int t = 0; t < 4; ++t) {
        #pragma unroll
        for (int i = 0; i < 8; ++i) {
            const int k = 4*g + (i & 3) + ((i >> 2) << 4);
            const int m = 16*t + ml;
            float v = (k < 30) ? w1[m*30 + k] : ((k == 30) ? b1[m] : 0.0f);
            A1[t][i] = (short)f2bf(v);
        }
    }
    #pragma unroll
    for (int t = 0; t < 2; ++t)
        #pragma unroll
        for (int s = 0; s < 2; ++s)
            #pragma unroll
            for (int i = 0; i < 8; ++i) {
                const int k = 4*g + (i & 3) + ((i >> 2) << 4);
                A2[t][s][i] = (short)f2bf(w2[(16*t + ml)*64 + 32*s + k]);
            }
    #pragma unroll
    for (int i = 0; i < 8; ++i) {
        const int k = 4*g + (i & 3) + ((i >> 2) << 4);
        A3[i] = (short)f2bf(w3[ml*32 + k]);
        float v4 = 0.0f, v5 = 0.0f;
        if (ml < 8) v4 = (k < 16) ? w4[ml*16 + k] : ((k == 16) ? b4[ml] : 0.0f);
        if (ml < 2) v5 = (k <  8) ? w5[ml*8  + k] : ((k ==  8) ? b5[ml] : 0.0f);
        A4[i] = (short)f2bf(v4);
        A5[i] = (short)f2bf(v5);
    }
    f32x4 bias2[2], bias3;
    #pragma unroll
    for (int t = 0; t < 2; ++t)
        #pragma unroll
        for (int q = 0; q < 4; ++q)
            bias2[t][q] = b2[16*t + 4*g + q];
    #pragma unroll
    for (int q = 0; q < 4; ++q)
        bias3[q] = b3[4*g + q];

    // ---- pair loop: 2 tiles (32 rows)/iter, single in-place reg set ----
    const int ntiles = (n + 15) >> 4;
    const int npairs = (ntiles + 1) >> 1;
    const int NW = gridDim.x * 4;
    const int p0 = blockIdx.x * 4 + wv;
    if (p0 >= npairs) return;

    const size_t xbytes = (size_t)n * 120;

    auto loadpair = [&](int pr, f32x4 r[4], int& delta) {
        size_t gb = (size_t)pr * 3840;
        if (gb + 4096 > xbytes) gb = xbytes - 4096;   // n >= 35 rows
        delta = (int)((size_t)pr * 3840 - gb);        // multiple of 16
        const unsigned char* gp = (const unsigned char*)x + gb + (size_t)lane * 16;
        r[0] = *(const f32x4*)(gp);
        r[1] = *(const f32x4*)(gp + 1024);
        r[2] = *(const f32x4*)(gp + 2048);
        r[3] = *(const f32x4*)(gp + 3072);
    };

    f32x4 rA[4];
    int deltaA = 0;
    loadpair(p0, rA, deltaA);

    const f32x4 zero = {0.0f, 0.0f, 0.0f, 0.0f};

    for (int p = p0; p < npairs; p += NW) {
        const int dcur = deltaA;

        // ---- write current pair's registers to LDS (vmcnt wait inserted by
        //      compiler for rA; DS ops wave-ordered) ----
        {
            unsigned char* lp = myL + lane * 16;
            *(f32x4*)(lp)        = rA[0];
            *(f32x4*)(lp + 1024) = rA[1];
            *(f32x4*)(lp + 2048) = rA[2];
            *(f32x4*)(lp + 3072) = rA[3];
        }

        // ---- rA regs are dead after the ds_writes: reload IN-PLACE with the
        //      next pair; loads fly under B0 build + the whole MFMA chain ----
        const int pn = p + NW;
        if (pn < npairs) loadpair(pn, rA, deltaA);

        // ---- build B0 for the 2 tiles of this pair ----
        s16x8 B0[2];
        const bool fullpair = ((p + 1) * 32 <= n);
        if (fullpair) {
            const float* L = (const float*)(myL + dcur);
            #pragma unroll
            for (int j = 0; j < 2; ++j) {
                const float* rp = L + (16*j + ml) * 30 + 4*g;
                float2 a01 = *(const float2*)(rp);
                float2 a23 = *(const float2*)(rp + 2);
                float2 b01 = *(const float2*)(rp + 16);   // g==3: floats 28,29 (real)
                float2 b23 = *(const float2*)(rp + 18);   // g<3 only (real data)
                u32x4 u;
                u.x = pkbf(a01.x, a01.y); u.y = pkbf(a23.x, a23.y);
                u.z = pkbf(b01.x, b01.y);
                // g==3: k=30 slot = 1.0 (multiplies A1's b1 column), k=31 = 0
                u.w = (g == 3) ? 0x00003F80u : pkbf(b23.x, b23.y);
                B0[j] = __builtin_bit_cast(s16x8, u);
            }
        } else {
            // tail pair (n % 32 != 0): direct clamped global reads
            #pragma unroll
            for (int j = 0; j < 2; ++j) {
                int row = p*32 + 16*j + ml;
                if (row >= n) row = n - 1;
                const float* rp = x + (size_t)row * 30 + 4*g;
                float2 a01 = *(const float2*)(rp);
                float2 a23 = *(const float2*)(rp + 2);
                float2 b01 = *(const float2*)(rp + 16);
                float2 b23 = (g < 3) ? *(const float2*)(rp + 18) : make_float2(0.f, 0.f);
                u32x4 u;
                u.x = pkbf(a01.x, a01.y); u.y = pkbf(a23.x, a23.y);
                u.z = pkbf(b01.x, b01.y);
                u.w = (g == 3) ? 0x00003F80u : pkbf(b23.x, b23.y);
                B0[j] = __builtin_bit_cast(s16x8, u);
            }
        }

        // ---- layer 1: 30(+bias via k=30)->64, C-init zero ----
        f32x4 c1[2][4];
        #pragma unroll
        for (int t = 0; t < 4; ++t)
            #pragma unroll
            for (int j = 0; j < 2; ++j)
                c1[j][t] = MFMA(A1[t], B0[j], zero);

        // ---- layer 2: 64->32 (K = 2 steps) ----
        s16x8 B1[2][2];
        #pragma unroll
        for (int j = 0; j < 2; ++j)
            #pragma unroll
            for (int s = 0; s < 2; ++s) {
                u32x4 u;
                u.x = rp2(c1[j][2*s][0],     c1[j][2*s][1]);
                u.y = rp2(c1[j][2*s][2],     c1[j][2*s][3]);
                u.z = rp2(c1[j][2*s + 1][0], c1[j][2*s + 1][1]);
                u.w = rp2(c1[j][2*s + 1][2], c1[j][2*s + 1][3]);
                B1[j][s] = __builtin_bit_cast(s16x8, u);
            }
        f32x4 c2[2][2];
        #pragma unroll
        for (int t = 0; t < 2; ++t)
            #pragma unroll
            for (int j = 0; j < 2; ++j) {
                f32x4 a = bias2[t];
                #pragma unroll
                for (int s = 0; s < 2; ++s) a = MFMA(A2[t][s], B1[j][s], a);
                c2[j][t] = a;
            }

        // ---- layer 3: 32->16 ----
        f32x4 c3[2];
        #pragma unroll
        for (int j = 0; j < 2; ++j) {
            u32x4 u2;
            u2.x = rp2(c2[j][0][0], c2[j][0][1]);
            u2.y = rp2(c2[j][0][2], c2[j][0][3]);
            u2.z = rp2(c2[j][1][0], c2[j][1][1]);
            u2.w = rp2(c2[j][1][2], c2[j][1][3]);
            c3[j] = MFMA(A3, __builtin_bit_cast(s16x8, u2), bias3);
        }

        // ---- layer 4: 16(+bias)->8 ----
        f32x4 c4[2];
        #pragma unroll
        for (int j = 0; j < 2; ++j) {
            u32x4 u3;
            u3.x = rp2(c3[j][0], c3[j][1]);
            u3.y = rp2(c3[j][2], c3[j][3]);
            u3.z = (g == 0) ? 0x3F80u : 0u;   // k==16 slot = 1.0 (bias)
            u3.w = 0u;
            c4[j] = MFMA(A4, __builtin_bit_cast(s16x8, u3), zero);
        }

        // ---- layer 5: 8(+bias)->2 (no ReLU) ----
        f32x4 c5[2];
        #pragma unroll
        for (int j = 0; j < 2; ++j) {
            // c4 == 0 exactly for g >= 2 (A4 rows m>=8 are zero), so rp2 gives 0.
            u32x4 u4;
            u4.x = (g == 2) ? 0x3F80u : rp2(c4[j][0], c4[j][1]);  // k==8 slot = bias
            u4.y = (g == 2) ? 0u      : rp2(c4[j][2], c4[j][3]);
            u4.z = 0u; u4.w = 0u;
            c5[j] = MFMA(A5, __builtin_bit_cast(s16x8, u4), zero);
        }

        // ---- store ----
        #pragma unroll
        for (int j = 0; j < 2; ++j) {
            const int orow = (2*p + j)*16 + lane;   // lanes 0..15: m=0,1 -> c5[0],c5[1]
            if (lane < 16 && orow < n) {
                float2 o; o.x = c5[j][0]; o.y = c5[j][1];
                *(float2*)(out + (size_t)orow * 2) = o;
            }
        }
    }
}

extern "C" void kernel_launch(void* const* d_in, const int* in_sizes, int n_in,
                              void* d_out, int out_size, void* d_ws, size_t ws_size,
                              hipStream_t stream) {
    const float* x  = (const float*)d_in[0];
    const float* w1 = (const float*)d_in[1];
    const float* b1 = (const float*)d_in[2];
    const float* w2 = (const float*)d_in[3];
    const float* b2 = (const float*)d_in[4];
    const float* w3 = (const float*)d_in[5];
    const float* b3 = (const float*)d_in[6];
    const float* w4 = (const float*)d_in[7];
    const float* b4 = (const float*)d_in[8];
    const float* w5 = (const float*)d_in[9];
    const float* b5 = (const float*)d_in[10];
    float* out = (float*)d_out;

    const int n = in_sizes[0] / 30;           // 1,000,000 rows
    const int ntiles = (n + 15) >> 4;         // 62,500
    const int npairs = (ntiles + 1) >> 1;     // 31,250
    // LDS 17.4 KB/block -> 8 blocks/CU fit (139 KB); VGPR band decides waves.
    int blocks = (npairs + 3) / 4;
    if (blocks > 2048) blocks = 2048;         // 8192 waves, ~3.8 pairs/wave

    mlp_mfma_kernel<<<blocks, 256, 0, stream>>>(
        x, w1, b1, w2, b2, w3, b3, w4, b4, w5, b5, out, n);
}

// Round 22
// 41.460 us; speedup vs baseline: 1.0518x; 1.0518x over previous
//
#include <hip/hip_runtime.h>
#include <hip/hip_bf16.h>

// 5-layer MLP 30->64->32->16->8->2 with ReLU, bf16 MFMA (16x16x32), batch tile N=16.
// Register-resident layer chain (k-slot map k = 4g+(i&3)+16*(i>>2); C/D layout
// m = 16t+4g+q, same lane group -> inter-layer repack is lane-local).
//
// FINAL (Round 22) = Round-15 champion VERBATIM: 41.3 us, best of 14 structural
// variants (163 -> 41.3 us over the session). Staging: global_load_dwordx4 into
// VGPRs -> ds_write -> ds_read (register staging; compiler inserts exact
// waits), depth-1 register prefetch, 2 tiles (32 rows)/iteration/wave.
// Session evidence: MFMA ~6%, VALU ~27%, HBM ~11%, LDS-conflicts 0 -- the
// kernel is bound by the serial per-pair dependency chain (pack->MFMA x5
// layers) times ~4 waves/SIMD effective overlap; occupancy/depth/ILP/pack
// levers all nulled or regressed (VGPR feedback loop). Structural plateau.

typedef float        f32x4 __attribute__((ext_vector_type(4)));
typedef unsigned int u32x4 __attribute__((ext_vector_type(4)));
typedef short        s16x8 __attribute__((ext_vector_type(8)));

// a -> low 16 bits, b -> high 16 bits; round-half-up (proven R14/R15)
static __device__ __forceinline__ unsigned int pkbf(float a, float b) {
    unsigned int ua = __builtin_bit_cast(unsigned int, a) + 0x8000u;
    unsigned int ub = __builtin_bit_cast(unsigned int, b) + 0x8000u;
    return __builtin_amdgcn_perm(ub, ua, 0x07060302u);
}
static __device__ __forceinline__ unsigned int rp2(float a, float b) {
    return pkbf(fmaxf(a, 0.0f), fmaxf(b, 0.0f));
}
// weights (preamble only): exact RNE via header
static __device__ __forceinline__ unsigned short f2bf(float f) {
    __hip_bfloat16 h = __float2bfloat16(f);
    unsigned short r;
    __builtin_memcpy(&r, &h, sizeof(r));
    return r;
}

#define MFMA(A, B, C) __builtin_amdgcn_mfma_f32_16x16x32_bf16((A), (B), (C), 0, 0, 0)

// Per-wave LDS: ONE slot of 4096 B window + 256 B zeroed pad.
#define SLOT_B 4352

__global__ __launch_bounds__(256) void mlp_mfma_kernel(
    const float* __restrict__ x,
    const float* __restrict__ w1, const float* __restrict__ b1,
    const float* __restrict__ w2, const float* __restrict__ b2,
    const float* __restrict__ w3, const float* __restrict__ b3,
    const float* __restrict__ w4, const float* __restrict__ b4,
    const float* __restrict__ w5, const float* __restrict__ b5,
    float* __restrict__ out, int n)
{
    __shared__ __attribute__((aligned(16))) unsigned char ldsX[4][SLOT_B];

    const int lane = threadIdx.x & 63;
    const int wv   = threadIdx.x >> 6;
    const int g    = lane >> 4;
    const int ml   = lane & 15;

    unsigned char* myL = &ldsX[wv][0];

    // zero the 256 B pad (row-31 g==3 overread must be finite; 0 * 0-wt = 0)
    *(unsigned int*)(myL + 4096 + lane * 4) = 0u;

    // ---- per-wave weight / bias fragment build ----
    s16x8 A1[4], A2[2][2], A3, A4, A5;
    #pragma unroll
    for (int t = 0; t < 4; ++t) {
        #pragma unroll
        for (int i = 0; i < 8; ++i) {
            const int k = 4*g + (i & 3) + ((i >> 2) << 4);
            const int m = 16*t + ml;
            float v = (k < 30) ? w1[m*30 + k] : 0.0f;   // k=30,31 zero (bias via acc)
            A1[t][i] = (short)f2bf(v);
        }
    }
    #pragma unroll
    for (int t = 0; t < 2; ++t)
        #pragma unroll
        for (int s = 0; s < 2; ++s)
            #pragma unroll
            for (int i = 0; i < 8; ++i) {
                const int k = 4*g + (i & 3) + ((i >> 2) << 4);
                A2[t][s][i] = (short)f2bf(w2[(16*t + ml)*64 + 32*s + k]);
            }
    #pragma unroll
    for (int i = 0; i < 8; ++i) {
        const int k = 4*g + (i & 3) + ((i >> 2) << 4);
        A3[i] = (short)f2bf(w3[ml*32 + k]);
        float v4 = 0.0f, v5 = 0.0f;
        if (ml < 8) v4 = (k < 16) ? w4[ml*16 + k] : ((k == 16) ? b4[ml] : 0.0f);
        if (ml < 2) v5 = (k <  8) ? w5[ml*8  + k] : ((k ==  8) ? b5[ml] : 0.0f);
        A4[i] = (short)f2bf(v4);
        A5[i] = (short)f2bf(v5);
    }
    f32x4 bias1[4], bias2[2], bias3;
    #pragma unroll
    for (int t = 0; t < 4; ++t)
        #pragma unroll
        for (int q = 0; q < 4; ++q)
            bias1[t][q] = b1[16*t + 4*g + q];
    #pragma unroll
    for (int t = 0; t < 2; ++t)
        #pragma unroll
        for (int q = 0; q < 4; ++q)
            bias2[t][q] = b2[16*t + 4*g + q];
    #pragma unroll
    for (int q = 0; q < 4; ++q)
        bias3[q] = b3[4*g + q];

    // ---- pair loop: 2 tiles (32 rows) per iteration, reg-staged prefetch ----
    const int ntiles = (n + 15) >> 4;
    const int npairs = (ntiles + 1) >> 1;
    const int NW = gridDim.x * 4;
    const int p0 = blockIdx.x * 4 + wv;
    if (p0 >= npairs) return;

    const size_t xbytes = (size_t)n * 120;

    // load a 4096 B window covering pair pr into 4 VGPR quads; delta = byte
    // shift of the pair's row 0 within the window (nonzero only when clamped)
    auto loadpair = [&](int pr, f32x4 r[4], int& delta) {
        size_t gb = (size_t)pr * 3840;
        if (gb + 4096 > xbytes) gb = xbytes - 4096;   // n >= 35 rows
        delta = (int)((size_t)pr * 3840 - gb);        // multiple of 16
        const unsigned char* gp = (const unsigned char*)x + gb + (size_t)lane * 16;
        r[0] = *(const f32x4*)(gp);
        r[1] = *(const f32x4*)(gp + 1024);
        r[2] = *(const f32x4*)(gp + 2048);
        r[3] = *(const f32x4*)(gp + 3072);
    };

    f32x4 rA[4], rB[4];
    int deltaA = 0, deltaB = 0;
    loadpair(p0, rA, deltaA);

    const f32x4 zero = {0.0f, 0.0f, 0.0f, 0.0f};

    for (int p = p0; p < npairs; p += NW) {
        // ---- write current pair's registers to LDS (compiler inserts the
        //      exact vmcnt wait for rA; DS ops are wave-ordered) ----
        {
            unsigned char* lp = myL + lane * 16;
            *(f32x4*)(lp)        = rA[0];
            *(f32x4*)(lp + 1024) = rA[1];
            *(f32x4*)(lp + 2048) = rA[2];
            *(f32x4*)(lp + 3072) = rA[3];
        }

        // ---- build B0 for the 2 tiles of this pair ----
        s16x8 B0[2];
        const bool fullpair = ((p + 1) * 32 <= n);
        if (fullpair) {
            const float* L = (const float*)(myL + deltaA);
            #pragma unroll
            for (int j = 0; j < 2; ++j) {
                const float* rp = L + (16*j + ml) * 30 + 4*g;
                float2 a01 = *(const float2*)(rp);
                float2 a23 = *(const float2*)(rp + 2);
                float2 b01 = *(const float2*)(rp + 16);   // g==3: floats 28,29 (real)
                float2 b23 = *(const float2*)(rp + 18);   // g==3: window/pad, x0 weights
                u32x4 u;
                u.x = pkbf(a01.x, a01.y); u.y = pkbf(a23.x, a23.y);
                u.z = pkbf(b01.x, b01.y); u.w = pkbf(b23.x, b23.y);
                B0[j] = __builtin_bit_cast(s16x8, u);
            }
        } else {
            // tail pair (n % 32 != 0): direct clamped global reads
            #pragma unroll
            for (int j = 0; j < 2; ++j) {
                int row = p*32 + 16*j + ml;
                if (row >= n) row = n - 1;
                const float* rp = x + (size_t)row * 30 + 4*g;
                float2 a01 = *(const float2*)(rp);
                float2 a23 = *(const float2*)(rp + 2);
                float2 b01 = *(const float2*)(rp + 16);
                float2 b23 = (g < 3) ? *(const float2*)(rp + 18) : make_float2(0.f, 0.f);
                u32x4 u;
                u.x = pkbf(a01.x, a01.y); u.y = pkbf(a23.x, a23.y);
                u.z = pkbf(b01.x, b01.y); u.w = pkbf(b23.x, b23.y);
                B0[j] = __builtin_bit_cast(s16x8, u);
            }
        }

        // ---- prefetch next pair into the alternate register set; the loads
        //      fly under the whole MFMA chain below ----
        const int pn = p + NW;
        if (pn < npairs) loadpair(pn, rB, deltaB);

        // ---- layer 1: 30->64 (bias in accumulator) ----
        f32x4 c1[2][4];
        #pragma unroll
        for (int t = 0; t < 4; ++t)
            #pragma unroll
            for (int j = 0; j < 2; ++j)
                c1[j][t] = MFMA(A1[t], B0[j], bias1[t]);

        // ---- layer 2: 64->32 (K = 2 steps) ----
        s16x8 B1[2][2];
        #pragma unroll
        for (int j = 0; j < 2; ++j)
            #pragma unroll
            for (int s = 0; s < 2; ++s) {
                u32x4 u;
                u.x = rp2(c1[j][2*s][0],     c1[j][2*s][1]);
                u.y = rp2(c1[j][2*s][2],     c1[j][2*s][3]);
                u.z = rp2(c1[j][2*s + 1][0], c1[j][2*s + 1][1]);
                u.w = rp2(c1[j][2*s + 1][2], c1[j][2*s + 1][3]);
                B1[j][s] = __builtin_bit_cast(s16x8, u);
            }
        f32x4 c2[2][2];
        #pragma unroll
        for (int t = 0; t < 2; ++t)
            #pragma unroll
            for (int j = 0; j < 2; ++j) {
                f32x4 a = bias2[t];
                #pragma unroll
                for (int s = 0; s < 2; ++s) a = MFMA(A2[t][s], B1[j][s], a);
                c2[j][t] = a;
            }

        // ---- layer 3: 32->16 ----
        f32x4 c3[2];
        #pragma unroll
        for (int j = 0; j < 2; ++j) {
            u32x4 u2;
            u2.x = rp2(c2[j][0][0], c2[j][0][1]);
            u2.y = rp2(c2[j][0][2], c2[j][0][3]);
            u2.z = rp2(c2[j][1][0], c2[j][1][1]);
            u2.w = rp2(c2[j][1][2], c2[j][1][3]);
            c3[j] = MFMA(A3, __builtin_bit_cast(s16x8, u2), bias3);
        }

        // ---- layer 4: 16(+bias)->8 ----
        f32x4 c4[2];
        #pragma unroll
        for (int j = 0; j < 2; ++j) {
            u32x4 u3;
            u3.x = rp2(c3[j][0], c3[j][1]);
            u3.y = rp2(c3[j][2], c3[j][3]);
            u3.z = (g == 0) ? 0x3F80u : 0u;   // k==16 slot = 1.0 (bias)
            u3.w = 0u;
            c4[j] = MFMA(A4, __builtin_bit_cast(s16x8, u3), zero);
        }

        // ---- layer 5: 8(+bias)->2 (no ReLU) ----
        f32x4 c5[2];
        #pragma unroll
        for (int j = 0; j < 2; ++j) {
            // c4 == 0 exactly for g >= 2 (A4 rows m>=8 are zero), so rp2 gives 0.
            u32x4 u4;
            u4.x = (g == 2) ? 0x3F80u : rp2(c4[j][0], c4[j][1]);  // k==8 slot = bias
            u4.y = (g == 2) ? 0u      : rp2(c4[j][2], c4[j][3]);
            u4.z = 0u; u4.w = 0u;
            c5[j] = MFMA(A5, __builtin_bit_cast(s16x8, u4), zero);
        }

        // ---- store ----
        #pragma unroll
        for (int j = 0; j < 2; ++j) {
            const int orow = (2*p + j)*16 + lane;   // lanes 0..15: m=0,1 -> c5[0],c5[1]
            if (lane < 16 && orow < n) {
                float2 o; o.x = c5[j][0]; o.y = c5[j][1];
                *(float2*)(out + (size_t)orow * 2) = o;
            }
        }

        // rotate the staged registers
        #pragma unroll
        for (int q = 0; q < 4; ++q) rA[q] = rB[q];
        deltaA = deltaB;
    }
}

extern "C" void kernel_launch(void* const* d_in, const int* in_sizes, int n_in,
                              void* d_out, int out_size, void* d_ws, size_t ws_size,
                              hipStream_t stream) {
    const float* x  = (const float*)d_in[0];
    const float* w1 = (const float*)d_in[1];
    const float* b1 = (const float*)d_in[2];
    const float* w2 = (const float*)d_in[3];
    const float* b2 = (const float*)d_in[4];
    const float* w3 = (const float*)d_in[5];
    const float* b3 = (const float*)d_in[6];
    const float* w4 = (const float*)d_in[7];
    const float* b4 = (const float*)d_in[8];
    const float* w5 = (const float*)d_in[9];
    const float* b5 = (const float*)d_in[10];
    float* out = (float*)d_out;

    const int n = in_sizes[0] / 30;           // 1,000,000 rows
    const int ntiles = (n + 15) >> 4;         // 62,500
    const int npairs = (ntiles + 1) >> 1;     // 31,250
    int blocks = (npairs + 3) / 4;
    if (blocks > 1280) blocks = 1280;         // R15 champion grid

    mlp_mfma_kernel<<<blocks, 256, 0, stream>>>(
        x, w1, b1, w2, b2, w3, b3, w4, b4, w5, b5, out, n);
}

// Round 23
// 40.840 us; speedup vs baseline: 1.0677x; 1.0152x over previous
//
#include <hip/hip_runtime.h>
#include <hip/hip_bf16.h>

// 5-layer MLP 30->64->32->16->8->2 with ReLU, bf16 MFMA (16x16x32), batch tile N=16.
// Register-resident layer chain (k-slot map k = 4g+(i&3)+16*(i>>2); C/D layout
// m = 16t+4g+q, same lane group -> inter-layer repack is lane-local).
// Round-23 = R15 champion with SCALARIZED wave-uniform addressing (single
// variable): readfirstlane-hoist wv so p/gb/delta/store-base math runs on
// SALU/SGPR (HK technique #5), loop-invariant LDS lane offsets hoisted.
// Rationale: kernel responds linearly to VALU instr count (R14: -100 instr
// predicted -2.5us, measured -3.2us); ~800 VALU/pair measured vs ~350
// intended; wave-uniform 64-bit address chains on the VALU are the
// identifiable chunk. Layout/pack/staging/grid byte-identical to champion.

typedef float        f32x4 __attribute__((ext_vector_type(4)));
typedef unsigned int u32x4 __attribute__((ext_vector_type(4)));
typedef short        s16x8 __attribute__((ext_vector_type(8)));

// a -> low 16 bits, b -> high 16 bits; round-half-up (proven R14/R15)
static __device__ __forceinline__ unsigned int pkbf(float a, float b) {
    unsigned int ua = __builtin_bit_cast(unsigned int, a) + 0x8000u;
    unsigned int ub = __builtin_bit_cast(unsigned int, b) + 0x8000u;
    return __builtin_amdgcn_perm(ub, ua, 0x07060302u);
}
static __device__ __forceinline__ unsigned int rp2(float a, float b) {
    return pkbf(fmaxf(a, 0.0f), fmaxf(b, 0.0f));
}
// weights (preamble only): exact RNE via header
static __device__ __forceinline__ unsigned short f2bf(float f) {
    __hip_bfloat16 h = __float2bfloat16(f);
    unsigned short r;
    __builtin_memcpy(&r, &h, sizeof(r));
    return r;
}

#define MFMA(A, B, C) __builtin_amdgcn_mfma_f32_16x16x32_bf16((A), (B), (C), 0, 0, 0)

// Per-wave LDS: ONE slot of 4096 B window + 256 B zeroed pad (R15 layout).
#define SLOT_B 4352

__global__ __launch_bounds__(256) void mlp_mfma_kernel(
    const float* __restrict__ x,
    const float* __restrict__ w1, const float* __restrict__ b1,
    const float* __restrict__ w2, const float* __restrict__ b2,
    const float* __restrict__ w3, const float* __restrict__ b3,
    const float* __restrict__ w4, const float* __restrict__ b4,
    const float* __restrict__ w5, const float* __restrict__ b5,
    float* __restrict__ out, int n)
{
    __shared__ __attribute__((aligned(16))) unsigned char ldsX[4][SLOT_B];

    const int lane = threadIdx.x & 63;
    // readfirstlane: prove wave-uniformity to the compiler -> SGPR dataflow
    const int wv   = __builtin_amdgcn_readfirstlane(threadIdx.x >> 6);
    const int g    = lane >> 4;
    const int ml   = lane & 15;

    unsigned char* myL = &ldsX[wv][0];

    // zero the 256 B pad (row-31 g==3 overread must be finite; 0 * 0-wt = 0)
    *(unsigned int*)(myL + 4096 + lane * 4) = 0u;

    // ---- per-wave weight / bias fragment build (identical to R15) ----
    s16x8 A1[4], A2[2][2], A3, A4, A5;
    #pragma unroll
    for (int t = 0; t < 4; ++t) {
        #pragma unroll
        for (int i = 0; i < 8; ++i) {
            const int k = 4*g + (i & 3) + ((i >> 2) << 4);
            const int m = 16*t + ml;
            float v = (k < 30) ? w1[m*30 + k] : 0.0f;   // k=30,31 zero (bias via acc)
            A1[t][i] = (short)f2bf(v);
        }
    }
    #pragma unroll
    for (int t = 0; t < 2; ++t)
        #pragma unroll
        for (int s = 0; s < 2; ++s)
            #pragma unroll
            for (int i = 0; i < 8; ++i) {
                const int k = 4*g + (i & 3) + ((i >> 2) << 4);
                A2[t][s][i] = (short)f2bf(w2[(16*t + ml)*64 + 32*s + k]);
            }
    #pragma unroll
    for (int i = 0; i < 8; ++i) {
        const int k = 4*g + (i & 3) + ((i >> 2) << 4);
        A3[i] = (short)f2bf(w3[ml*32 + k]);
        float v4 = 0.0f, v5 = 0.0f;
        if (ml < 8) v4 = (k < 16) ? w4[ml*16 + k] : ((k == 16) ? b4[ml] : 0.0f);
        if (ml < 2) v5 = (k <  8) ? w5[ml*8  + k] : ((k ==  8) ? b5[ml] : 0.0f);
        A4[i] = (short)f2bf(v4);
        A5[i] = (short)f2bf(v5);
    }
    f32x4 bias1[4], bias2[2], bias3;
    #pragma unroll
    for (int t = 0; t < 4; ++t)
        #pragma unroll
        for (int q = 0; q < 4; ++q)
            bias1[t][q] = b1[16*t + 4*g + q];
    #pragma unroll
    for (int t = 0; t < 2; ++t)
        #pragma unroll
        for (int q = 0; q < 4; ++q)
            bias2[t][q] = b2[16*t + 4*g + q];
    #pragma unroll
    for (int q = 0; q < 4; ++q)
        bias3[q] = b3[4*g + q];

    // ---- pair loop: 2 tiles (32 rows) per iteration, reg-staged prefetch ----
    const int ntiles = (n + 15) >> 4;
    const int npairs = (ntiles + 1) >> 1;
    const int NW = __builtin_amdgcn_readfirstlane(gridDim.x * 4);
    const int p0 = __builtin_amdgcn_readfirstlane((int)blockIdx.x * 4 + wv);
    if (p0 >= npairs) return;

    // x is 120 MB: 32-bit byte offsets suffice -> scalar (SGPR) index math
    const unsigned xbytes = (unsigned)n * 120u;
    const unsigned char* xb = (const unsigned char*)x;

    // loop-invariant per-lane offsets (hoisted once)
    const int vload_off = lane * 16;                 // global window voffset
    const int loff      = ml * 30 + 4 * g;           // LDS read base (floats)
    unsigned char* const lwp = myL + lane * 16;      // LDS write base

    // load the 4096 B window covering pair pr; delta = byte shift of the
    // pair's row 0 within the window (nonzero only for the clamped last pair)
    auto loadpair = [&](int pr, f32x4 r[4], int& delta) {
        unsigned gb = (unsigned)pr * 3840u;          // scalar mul
        if (gb + 4096u > xbytes) gb = xbytes - 4096u;
        delta = (int)((unsigned)pr * 3840u - gb);    // multiple of 16, uniform
        const unsigned char* gp = xb + gb;           // scalar base
        r[0] = *(const f32x4*)(gp + vload_off);
        r[1] = *(const f32x4*)(gp + vload_off + 1024);
        r[2] = *(const f32x4*)(gp + vload_off + 2048);
        r[3] = *(const f32x4*)(gp + vload_off + 3072);
    };

    f32x4 rA[4], rB[4];
    int deltaA = 0, deltaB = 0;
    loadpair(p0, rA, deltaA);

    const f32x4 zero = {0.0f, 0.0f, 0.0f, 0.0f};

    for (int p = p0; p < npairs; p += NW) {
        // ---- write current pair's registers to LDS (compiler inserts the
        //      exact vmcnt wait for rA; DS ops are wave-ordered) ----
        *(f32x4*)(lwp)        = rA[0];
        *(f32x4*)(lwp + 1024) = rA[1];
        *(f32x4*)(lwp + 2048) = rA[2];
        *(f32x4*)(lwp + 3072) = rA[3];

        // ---- build B0 for the 2 tiles of this pair ----
        s16x8 B0[2];
        const bool fullpair = ((p + 1) * 32 <= n);
        if (fullpair) {
            // deltaA is wave-uniform (scalar); loff is the per-lane part
            const float* L = (const float*)myL + (deltaA >> 2) + loff;
            #pragma unroll
            for (int j = 0; j < 2; ++j) {
                const float* rp = L + j * 480;       // 16 rows * 30 floats
                float2 a01 = *(const float2*)(rp);
                float2 a23 = *(const float2*)(rp + 2);
                float2 b01 = *(const float2*)(rp + 16);   // g==3: floats 28,29 (real)
                float2 b23 = *(const float2*)(rp + 18);   // g==3: window/pad, x0 weights
                u32x4 u;
                u.x = pkbf(a01.x, a01.y); u.y = pkbf(a23.x, a23.y);
                u.z = pkbf(b01.x, b01.y); u.w = pkbf(b23.x, b23.y);
                B0[j] = __builtin_bit_cast(s16x8, u);
            }
        } else {
            // tail pair (n % 32 != 0): direct clamped global reads
            #pragma unroll
            for (int j = 0; j < 2; ++j) {
                int row = p*32 + 16*j + ml;
                if (row >= n) row = n - 1;
                const float* rp = x + (size_t)row * 30 + 4*g;
                float2 a01 = *(const float2*)(rp);
                float2 a23 = *(const float2*)(rp + 2);
                float2 b01 = *(const float2*)(rp + 16);
                float2 b23 = (g < 3) ? *(const float2*)(rp + 18) : make_float2(0.f, 0.f);
                u32x4 u;
                u.x = pkbf(a01.x, a01.y); u.y = pkbf(a23.x, a23.y);
                u.z = pkbf(b01.x, b01.y); u.w = pkbf(b23.x, b23.y);
                B0[j] = __builtin_bit_cast(s16x8, u);
            }
        }

        // ---- prefetch next pair into the alternate register set; the loads
        //      fly under the whole MFMA chain below ----
        const int pn = p + NW;
        if (pn < npairs) loadpair(pn, rB, deltaB);

        // ---- layer 1: 30->64 (bias in accumulator) ----
        f32x4 c1[2][4];
        #pragma unroll
        for (int t = 0; t < 4; ++t)
            #pragma unroll
            for (int j = 0; j < 2; ++j)
                c1[j][t] = MFMA(A1[t], B0[j], bias1[t]);

        // ---- layer 2: 64->32 (K = 2 steps) ----
        s16x8 B1[2][2];
        #pragma unroll
        for (int j = 0; j < 2; ++j)
            #pragma unroll
            for (int s = 0; s < 2; ++s) {
                u32x4 u;
                u.x = rp2(c1[j][2*s][0],     c1[j][2*s][1]);
                u.y = rp2(c1[j][2*s][2],     c1[j][2*s][3]);
                u.z = rp2(c1[j][2*s + 1][0], c1[j][2*s + 1][1]);
                u.w = rp2(c1[j][2*s + 1][2], c1[j][2*s + 1][3]);
                B1[j][s] = __builtin_bit_cast(s16x8, u);
            }
        f32x4 c2[2][2];
        #pragma unroll
        for (int t = 0; t < 2; ++t)
            #pragma unroll
            for (int j = 0; j < 2; ++j) {
                f32x4 a = bias2[t];
                #pragma unroll
                for (int s = 0; s < 2; ++s) a = MFMA(A2[t][s], B1[j][s], a);
                c2[j][t] = a;
            }

        // ---- layer 3: 32->16 ----
        f32x4 c3[2];
        #pragma unroll
        for (int j = 0; j < 2; ++j) {
            u32x4 u2;
            u2.x = rp2(c2[j][0][0], c2[j][0][1]);
            u2.y = rp2(c2[j][0][2], c2[j][0][3]);
            u2.z = rp2(c2[j][1][0], c2[j][1][1]);
            u2.w = rp2(c2[j][1][2], c2[j][1][3]);
            c3[j] = MFMA(A3, __builtin_bit_cast(s16x8, u2), bias3);
        }

        // ---- layer 4: 16(+bias)->8 ----
        f32x4 c4[2];
        #pragma unroll
        for (int j = 0; j < 2; ++j) {
            u32x4 u3;
            u3.x = rp2(c3[j][0], c3[j][1]);
            u3.y = rp2(c3[j][2], c3[j][3]);
            u3.z = (g == 0) ? 0x3F80u : 0u;   // k==16 slot = 1.0 (bias)
            u3.w = 0u;
            c4[j] = MFMA(A4, __builtin_bit_cast(s16x8, u3), zero);
        }

        // ---- layer 5: 8(+bias)->2 (no ReLU) ----
        f32x4 c5[2];
        #pragma unroll
        for (int j = 0; j < 2; ++j) {
            // c4 == 0 exactly for g >= 2 (A4 rows m>=8 are zero), so rp2 gives 0.
            u32x4 u4;
            u4.x = (g == 2) ? 0x3F80u : rp2(c4[j][0], c4[j][1]);  // k==8 slot = bias
            u4.y = (g == 2) ? 0u      : rp2(c4[j][2], c4[j][3]);
            u4.z = 0u; u4.w = 0u;
            c5[j] = MFMA(A5, __builtin_bit_cast(s16x8, u4), zero);
        }

        // ---- store: scalar base (2p+j)*32 floats + per-lane lane*2 ----
        #pragma unroll
        for (int j = 0; j < 2; ++j) {
            const int orow = (2*p + j)*16 + lane;
            if (lane < 16 && orow < n) {
                float* op = out + (unsigned)(2*p + j) * 32u;  // uniform base
                float2 o; o.x = c5[j][0]; o.y = c5[j][1];
                *(float2*)(op + lane * 2) = o;
            }
        }

        // rotate the staged registers
        #pragma unroll
        for (int q = 0; q < 4; ++q) rA[q] = rB[q];
        deltaA = deltaB;
    }
}

extern "C" void kernel_launch(void* const* d_in, const int* in_sizes, int n_in,
                              void* d_out, int out_size, void* d_ws, size_t ws_size,
                              hipStream_t stream) {
    const float* x  = (const float*)d_in[0];
    const float* w1 = (const float*)d_in[1];
    const float* b1 = (const float*)d_in[2];
    const float* w2 = (const float*)d_in[3];
    const float* b2 = (const float*)d_in[4];
    const float* w3 = (const float*)d_in[5];
    const float* b3 = (const float*)d_in[6];
    const float* w4 = (const float*)d_in[7];
    const float* b4 = (const float*)d_in[8];
    const float* w5 = (const float*)d_in[9];
    const float* b5 = (const float*)d_in[10];
    float* out = (float*)d_out;

    const int n = in_sizes[0] / 30;           // 1,000,000 rows
    const int ntiles = (n + 15) >> 4;         // 62,500
    const int npairs = (ntiles + 1) >> 1;     // 31,250
    int blocks = (npairs + 3) / 4;
    if (blocks > 1280) blocks = 1280;         // champion grid (single-variable A/B)

    mlp_mfma_kernel<<<blocks, 256, 0, stream>>>(
        x, w1, b1, w2, b2, w3, b3, w4, b4, w5, b5, out, n);
}